// Round 3
// baseline (557.727 us; speedup 1.0000x reference)
//
#include <hip/hip_runtime.h>

#define DEV __device__ __forceinline__

typedef __attribute__((ext_vector_type(8))) short bf16x8;   // 8 bf16 in 4 VGPRs
typedef __attribute__((ext_vector_type(4))) float f32x4;

constexpr int Bc  = 32;
constexpr int Nc  = 512;
constexpr int Dc  = 1024;
constexpr int Hc  = 16;
constexpr int HDc = 64;
constexpr int SEGc= 64;
constexpr int Mrows = Bc * Nc;

// round-to-nearest-even f32 -> bf16 bit pattern
DEV unsigned short bf16r(float x) {
  union { float f; unsigned int u; } c; c.f = x;
  unsigned int r = (c.u + 0x7fffu + ((c.u >> 16) & 1u)) >> 16;
  return (unsigned short)r;
}

// async global->LDS, 16B per lane. LDS dest is wave-uniform base + lane*16.
DEV void async_ld16(const void* g, void* l) {
  __builtin_amdgcn_global_load_lds(
      (const __attribute__((address_space(1))) void*)g,
      (__attribute__((address_space(3))) void*)l,
      16, 0, 0);
}

// ------------------------------------------------------------- prep (merged)
// bid 0..1023    : Wq f32 -> WqTile bf16 (swizzled MFMA staging layout)
//                  idx = cb*524288 + kb*16384 + oct*4096 + (cl^(oct<<1))*8 + e
// bid 1024..2047 : Wo f32 -> WoTile bf16 (same idea, 8 col-panels of 128)
//                  idx = tn*131072 + kb*4096  + oct*1024 + (cl^(oct<<1))*8 + e
// bid 2048..2559 : router f32 -> Rg / RTg per-n 8KB blocks (XOR-swizzled octs)
// bid 2560..10751: query f32 -> query_b bf16 (row-major, 8 f32/thread)
__global__ __launch_bounds__(256)
void prep(const float* __restrict__ Wq, const float* __restrict__ Wo,
          const float* __restrict__ router, const float* __restrict__ query,
          unsigned short* __restrict__ wqt, unsigned short* __restrict__ wot,
          unsigned short* __restrict__ Rg, unsigned short* __restrict__ RTg,
          unsigned short* __restrict__ qb) {
  const int bid = blockIdx.x;
  if (bid < 2048) {
    __shared__ float tile[32][33];
    const bool isWq = bid < 1024;
    const int b2 = isWq ? bid : bid - 1024;
    const float* src = isWq ? Wq : Wo;
    const int bx = b2 & 31, by = b2 >> 5;               // bx: c-tile, by: k-tile
    const int tx = threadIdx.x & 31, ty = threadIdx.x >> 5;   // 32 x 8
    for (int i = 0; i < 4; ++i) {
      int r = ty + i * 8;
      tile[r][tx] = src[(size_t)(by * 32 + r) * 1024 + bx * 32 + tx];
    }
    __syncthreads();
    if (ty < 4) {                        // 128 threads: one 16B unit each
      const int oct = ty;                // k-oct within this 32-k step (kb=by)
      const int c = bx * 32 + tx;
      unsigned short tmp[8];
#pragma unroll
      for (int e = 0; e < 8; ++e) tmp[e] = bf16r(tile[oct * 8 + e][tx]);
      ushort4 u0, u1;
      u0.x = tmp[0]; u0.y = tmp[1]; u0.z = tmp[2]; u0.w = tmp[3];
      u1.x = tmp[4]; u1.y = tmp[5]; u1.z = tmp[6]; u1.w = tmp[7];
      size_t idx;
      if (isWq) {
        const int cbb = c >> 9, cl = c & 511;
        idx = (size_t)cbb * 524288 + (size_t)by * 16384
            + (size_t)oct * 4096 + (size_t)(cl ^ (oct << 1)) * 8;
        *(ushort4*)(wqt + idx) = u0; *(ushort4*)(wqt + idx + 4) = u1;
      } else {
        const int tn = c >> 7, cl = c & 127;
        idx = (size_t)tn * 131072 + (size_t)by * 4096
            + (size_t)oct * 1024 + (size_t)(cl ^ (oct << 1)) * 8;
        *(ushort4*)(wot + idx) = u0; *(ushort4*)(wot + idx + 4) = u1;
      }
    }
  } else if (bid < 2560) {
    const int nn = bid - 2048;           // 0..511
    const int t  = threadIdx.x;          // 256
    const int s  = t >> 2, dq = (t & 3) * 16;
    const float* p = router + ((size_t)s * 512 + nn) * 64 + dq;
    float v[16];
#pragma unroll
    for (int i = 0; i < 16; i += 4) {
      float4 f = *(const float4*)(p + i);
      v[i] = f.x; v[i+1] = f.y; v[i+2] = f.z; v[i+3] = f.w;
    }
    unsigned short bvv[16];
#pragma unroll
    for (int i = 0; i < 16; ++i) bvv[i] = bf16r(v[i]);
    unsigned short* rb = Rg + (size_t)nn * 4096 + s * 64;
#pragma unroll
    for (int o2 = 0; o2 < 2; ++o2) {
      int oct  = (dq >> 3) + o2;
      int phys = oct ^ (s & 7);
      ushort4 a, b2v;
      a.x   = bvv[o2*8+0]; a.y   = bvv[o2*8+1]; a.z   = bvv[o2*8+2]; a.w   = bvv[o2*8+3];
      b2v.x = bvv[o2*8+4]; b2v.y = bvv[o2*8+5]; b2v.z = bvv[o2*8+6]; b2v.w = bvv[o2*8+7];
      *(ushort4*)(rb + phys * 8)     = a;
      *(ushort4*)(rb + phys * 8 + 4) = b2v;
    }
    unsigned short* tb = RTg + (size_t)nn * 4096;
#pragma unroll
    for (int i = 0; i < 16; ++i) {
      int d = dq + i;
      tb[d * 64 + (((s >> 3) ^ (d & 7)) * 8) + (s & 7)] = bvv[i];
    }
  } else {
    // query f32 -> bf16, 8 elems per thread
    const size_t base = ((size_t)(bid - 2560) * 256 + threadIdx.x) * 8;
    float4 a = *(const float4*)(query + base);
    float4 b = *(const float4*)(query + base + 4);
    ushort4 u0, u1;
    u0.x = bf16r(a.x); u0.y = bf16r(a.y); u0.z = bf16r(a.z); u0.w = bf16r(a.w);
    u1.x = bf16r(b.x); u1.y = bf16r(b.y); u1.z = bf16r(b.z); u1.w = bf16r(b.w);
    *(ushort4*)(qb + base)     = u0;
    *(ushort4*)(qb + base + 4) = u1;
  }
}

// ---------------------------------------------------------------- GEMM (out)
// Barrier-free K-loop: A frags per-lane direct from global (bf16), B tiles
// wave-private LDS double-buffer via global_load_lds from pre-tiled WoTile,
// counted vmcnt(8) per step (never drained in-loop). out = recv @ Wo + bo.
__global__ __launch_bounds__(256, 4)
void gemm_bt(const unsigned short* __restrict__ A,     // (16384 x 1024) bf16
             const unsigned short* __restrict__ wot,   // WoTile bf16
             const float* __restrict__ bias,
             float* __restrict__ Cout) {
  __shared__ __align__(16) unsigned short lds[16384];  // 2 bufs x 4 waves x 2048
  const int tid = threadIdx.x, lane = tid & 63, wave = tid >> 6;
  const int tm = blockIdx.x >> 3, tn = blockIdx.x & 7;
  const int wm = (wave >> 1) * 64, wn = (wave & 1) * 64;
  const int la = lane & 15, quad = lane >> 4;

  f32x4 acc[4][4] = {};

  const unsigned short* aA[4];
#pragma unroll
  for (int rt = 0; rt < 4; ++rt)
    aA[rt] = A + (size_t)(tm * 128 + wm + rt * 16 + la) * 1024 + quad * 8;
  const unsigned short* wob = wot + (size_t)tn * 131072 + wn * 8 + lane * 8;
  unsigned short* wlds = lds + wave * 2048;            // + buf*8192 + p*512

  bf16x8 afA[4], afB[4];
  {   // prologue: A(0) regs, B(0) -> buf0
#pragma unroll
    for (int rt = 0; rt < 4; ++rt) afA[rt] = *(const bf16x8*)(aA[rt]);
#pragma unroll
    for (int p = 0; p < 4; ++p)
      async_ld16(wob + p * 1024, wlds + p * 512);
  }
  __builtin_amdgcn_sched_barrier(0);

  auto step = [&](int kb, bf16x8* afc, bf16x8* afn,
                  unsigned short* Bc_, unsigned short* Bn_,
                  bool last) __attribute__((always_inline)) {
    if (!last) {
#pragma unroll
      for (int rt = 0; rt < 4; ++rt)
        afn[rt] = *(const bf16x8*)(aA[rt] + (kb + 1) * 32);
#pragma unroll
      for (int p = 0; p < 4; ++p)
        async_ld16(wob + (size_t)(kb + 1) * 4096 + p * 1024, Bn_ + p * 512);
    }
    __builtin_amdgcn_sched_barrier(0);
    if (!last) asm volatile("s_waitcnt vmcnt(8)" ::: "memory");
    else       asm volatile("s_waitcnt vmcnt(0)" ::: "memory");
    __builtin_amdgcn_sched_barrier(0);
    bf16x8 bfr[4];
#pragma unroll
    for (int j = 0; j < 4; ++j)
      bfr[j] = *(const bf16x8*)(Bc_ + quad * 512
                                + ((j * 16 + la) ^ (quad << 1)) * 8);
#pragma unroll
    for (int rt = 0; rt < 4; ++rt)
#pragma unroll
      for (int j = 0; j < 4; ++j)
        acc[rt][j] = __builtin_amdgcn_mfma_f32_16x16x32_bf16(afc[rt], bfr[j],
                                                             acc[rt][j], 0, 0, 0);
  };

#pragma unroll 1
  for (int kb = 0; kb < 30; kb += 2) {
    step(kb,     afA, afB, wlds,        wlds + 8192, false);
    step(kb + 1, afB, afA, wlds + 8192, wlds,        false);
  }
  step(30, afA, afB, wlds,        wlds + 8192, false);
  step(31, afB, afA, wlds + 8192, wlds,        true);

  // ---- epilogue: LDS-staged coalesced f32 stores ----------------------
  const int colbase = tn * 128 + wn;
  float bv[4];
#pragma unroll
  for (int j = 0; j < 4; ++j) bv[j] = bias[colbase + j * 16 + la];

  float* eps = ((float*)lds) + wave * 1024;
  const int rowbase = tm * 128 + wm;

#pragma unroll
  for (int i = 0; i < 4; ++i) {
    __syncthreads();
#pragma unroll
    for (int j = 0; j < 4; ++j)
#pragma unroll
      for (int r = 0; r < 4; ++r)
        eps[(quad * 4 + r) * 64 + j * 16 + la] = acc[i][j][r] + bv[j];
    __syncthreads();
#pragma unroll
    for (int s = 0; s < 4; ++s) {
      int idx = s * 64 + lane;
      int row = idx >> 4, c4 = idx & 15;
      float4 v = *(const float4*)(eps + row * 64 + c4 * 4);
      *(float4*)(Cout + (size_t)(rowbase + i * 16 + row) * 1024
                 + colbase + c4 * 4) = v;
    }
  }
}

// ---------------------------------------------------------------- fused
// Grid 512 (2 blocks/CU, 68 KiB LDS). Block = 64 rows {32 b x 2 n} x 512 cols.
// Phase 1 (BARRIER-FREE): q = query_b @ Wq + bq into regs. A frags per-lane
// direct from global bf16; B (Wq) wave-private LDS double-buffer from the
// pre-swizzled WqTile; one counted vmcnt(8) per step. Phase 2: wave w owns
// head h = cbh*8 + w for both n, fully wave-private.
// LDS (shorts): Bbuf0 [0,16384) | Bbuf1 [16384,32768) ; phase-2 overlay:
// Rs 2x4096 @0, RTs 2x4096 @8192, per-wave QA @16384 + w*2304 (to 34816).
__global__ __launch_bounds__(512, 4)
void fused_qmid(const unsigned short* __restrict__ qb,    // (16384x1024) bf16
                const unsigned short* __restrict__ wqt,   // WqTile bf16
                const float* __restrict__ bq,
                const unsigned short* __restrict__ Rg,
                const unsigned short* __restrict__ RTg,
                float* __restrict__ attn_out,             // (B,H,N,S) f32
                unsigned short* __restrict__ recv_out) {  // (16384,1024) bf16
  __shared__ __align__(16) unsigned short lds[34816];
  const int tid = threadIdx.x, lane = tid & 63, w = tid >> 6;
  const int la = lane & 15, quad = lane >> 4;
  const int n0 = (blockIdx.x >> 1) * 2, cbh = blockIdx.x & 1;

  // ---- phase 1 (no barriers) -----------------------------------------
  f32x4 acc[4][4] = {};   // [row-tile rt][col-tile j]; row = rt*16+quad*4+r

  const unsigned short* aA[4];
#pragma unroll
  for (int rt = 0; rt < 4; ++rt) {
    int rho = rt * 16 + la;                    // rho = nl*32 + b
    aA[rt] = qb + ((size_t)((rho & 31) * 512 + n0 + (rho >> 5))) * 1024
           + quad * 8;
  }
  const unsigned short* wqb = wqt + (size_t)cbh * 524288 + w * 512 + lane * 8;
  unsigned short* wlds = lds + w * 512;        // + buf*16384 + p*4096

  bf16x8 afA[4], afB[4];
  {   // prologue: A(0) regs, B(0) -> buf0
#pragma unroll
    for (int rt = 0; rt < 4; ++rt) afA[rt] = *(const bf16x8*)(aA[rt]);
#pragma unroll
    for (int p = 0; p < 4; ++p)
      async_ld16(wqb + p * 4096, wlds + p * 4096);
  }
  __builtin_amdgcn_sched_barrier(0);

  auto step = [&](int kb, bf16x8* afc, bf16x8* afn,
                  unsigned short* Bc_, unsigned short* Bn_,
                  bool last) __attribute__((always_inline)) {
    if (!last) {
#pragma unroll
      for (int rt = 0; rt < 4; ++rt)
        afn[rt] = *(const bf16x8*)(aA[rt] + (kb + 1) * 32);
#pragma unroll
      for (int p = 0; p < 4; ++p)
        async_ld16(wqb + (size_t)(kb + 1) * 16384 + p * 4096, Bn_ + p * 4096);
    }
    __builtin_amdgcn_sched_barrier(0);
    if (!last) asm volatile("s_waitcnt vmcnt(8)" ::: "memory");
    else       asm volatile("s_waitcnt vmcnt(0)" ::: "memory");
    __builtin_amdgcn_sched_barrier(0);
    bf16x8 bfr[4];
#pragma unroll
    for (int j = 0; j < 4; ++j)
      bfr[j] = *(const bf16x8*)(Bc_ + quad * 4096
                                + ((j * 16 + la) ^ (quad << 1)) * 8);
#pragma unroll
    for (int rt = 0; rt < 4; ++rt)
#pragma unroll
      for (int j = 0; j < 4; ++j)
        acc[rt][j] = __builtin_amdgcn_mfma_f32_16x16x32_bf16(afc[rt], bfr[j],
                                                             acc[rt][j], 0, 0, 0);
  };

#pragma unroll 1
  for (int kb = 0; kb < 30; kb += 2) {
    step(kb,     afA, afB, wlds,         wlds + 16384, false);
    step(kb + 1, afB, afA, wlds + 16384, wlds,         false);
  }
  step(30, afA, afB, wlds,         wlds + 16384, false);
  step(31, afB, afA, wlds + 16384, wlds,         true);

  // bias (f32, before bf16 repack)
  float bv[4];
#pragma unroll
  for (int j = 0; j < 4; ++j) bv[j] = bq[cbh * 512 + (w * 4 + j) * 16 + la];
#pragma unroll
  for (int rt = 0; rt < 4; ++rt)
#pragma unroll
    for (int j = 0; j < 4; ++j)
#pragma unroll
      for (int r = 0; r < 4; ++r) acc[rt][j][r] += bv[j];

  // ---- phase-2 staging: R/RT over the (now dead) B buffers ------------
  __syncthreads();                 // all waves done with B LDS
  {
    const int bslot = w * 512 + lane * 8;
#pragma unroll
    for (int q2 = 0; q2 < 4; ++q2) {
      const unsigned short* srcb = (q2 < 2)
          ? (Rg  + (size_t)(n0 + q2)     * 4096)
          : (RTg + (size_t)(n0 + q2 - 2) * 4096);
      async_ld16(srcb + bslot, lds + q2 * 4096 + w * 512);
    }
  }
  __syncthreads();                 // drains vmcnt: R/RT staged

  // ---- phase 2: wave-private, head h = cbh*8 + w ----------------------
  const int h = cbh * 8 + w;
  unsigned short* QA = lds + 16384 + w * 2304;   // [32 b][72], Qs then AT

#pragma unroll
  for (int nl = 0; nl < 2; ++nl) {
    const int nn = n0 + nl;

    // 1. repack q slice -> QA (bf16)
#pragma unroll
    for (int rt2 = 0; rt2 < 2; ++rt2)
#pragma unroll
      for (int j4 = 0; j4 < 4; ++j4)
#pragma unroll
        for (int r = 0; r < 4; ++r)
          QA[(rt2 * 16 + quad * 4 + r) * 72 + j4 * 16 + la]
              = bf16r(acc[nl * 2 + rt2][j4][r]);

    // 2. frags
    bf16x8 qf[2][2], rf[4][2];
#pragma unroll
    for (int bt = 0; bt < 2; ++bt)
#pragma unroll
      for (int kc = 0; kc < 2; ++kc)
        qf[bt][kc] = *(const bf16x8*)(QA + (bt * 16 + la) * 72
                                      + (kc * 4 + quad) * 8);
    const unsigned short* Rn = lds + nl * 4096;
#pragma unroll
    for (int st = 0; st < 4; ++st)
#pragma unroll
      for (int kc = 0; kc < 2; ++kc) {
        int s_ = st * 16 + la;
        rf[st][kc] = *(const bf16x8*)(Rn + s_ * 64
                                      + ((kc * 4 + quad) ^ (s_ & 7)) * 8);
      }

    // 3. scores^T = R * q^T : rows s, cols b
    f32x4 sacc[2][4] = {};
#pragma unroll
    for (int bt = 0; bt < 2; ++bt)
#pragma unroll
      for (int st = 0; st < 4; ++st) {
        sacc[bt][st] = __builtin_amdgcn_mfma_f32_16x16x32_bf16(rf[st][0], qf[bt][0], sacc[bt][st], 0, 0, 0);
        sacc[bt][st] = __builtin_amdgcn_mfma_f32_16x16x32_bf16(rf[st][1], qf[bt][1], sacc[bt][st], 0, 0, 0);
      }

    // 4. softmax over s per column b; attn stores + AT writes (QA reuse)
#pragma unroll
    for (int bt = 0; bt < 2; ++bt) {
      float mx = sacc[bt][0][0];
#pragma unroll
      for (int st = 0; st < 4; ++st)
#pragma unroll
        for (int r = 0; r < 4; ++r) mx = fmaxf(mx, sacc[bt][st][r]);
      mx = fmaxf(mx, __shfl_xor(mx, 16));
      mx = fmaxf(mx, __shfl_xor(mx, 32));
      float sum = 0.f;
#pragma unroll
      for (int st = 0; st < 4; ++st)
#pragma unroll
        for (int r = 0; r < 4; ++r) {
          float e = __expf(sacc[bt][st][r] - mx);
          sacc[bt][st][r] = e; sum += e;
        }
      sum += __shfl_xor(sum, 16);
      sum += __shfl_xor(sum, 32);
      float inv = 1.0f / sum;
#pragma unroll
      for (int st = 0; st < 4; ++st) {
        sacc[bt][st][0] *= inv; sacc[bt][st][1] *= inv;
        sacc[bt][st][2] *= inv; sacc[bt][st][3] *= inv;
      }
      const int b_ = bt * 16 + la;
      float* ao = attn_out + ((size_t)(b_ * 16 + h) * 512 + nn) * 64 + quad * 4;
#pragma unroll
      for (int st = 0; st < 4; ++st) {
        *(float4*)(ao + st * 16) = *(float4*)(&sacc[bt][st]);
        ushort4 u;
        u.x = bf16r(sacc[bt][st][0]); u.y = bf16r(sacc[bt][st][1]);
        u.z = bf16r(sacc[bt][st][2]); u.w = bf16r(sacc[bt][st][3]);
        *(ushort4*)(QA + b_ * 72 + st * 16 + quad * 4) = u;
      }
    }

    // 5. recv^T = R^T * attn^T : rows d, cols b
    __asm__ volatile("s_waitcnt lgkmcnt(0)" ::: "memory");
    bf16x8 atf[2][2], rtf2[4][2];
#pragma unroll
    for (int bt = 0; bt < 2; ++bt)
#pragma unroll
      for (int kc = 0; kc < 2; ++kc)
        atf[bt][kc] = *(const bf16x8*)(QA + (bt * 16 + la) * 72
                                       + (kc * 4 + quad) * 8);
    const unsigned short* RTn = lds + 8192 + nl * 4096;
#pragma unroll
    for (int dt = 0; dt < 4; ++dt)
#pragma unroll
      for (int kc = 0; kc < 2; ++kc) {
        int d_ = dt * 16 + la;
        rtf2[dt][kc] = *(const bf16x8*)(RTn + d_ * 64
                                        + ((kc * 4 + quad) ^ (d_ & 7)) * 8);
      }
    f32x4 racc[2][4] = {};
#pragma unroll
    for (int bt = 0; bt < 2; ++bt)
#pragma unroll
      for (int dt = 0; dt < 4; ++dt) {
        racc[bt][dt] = __builtin_amdgcn_mfma_f32_16x16x32_bf16(rtf2[dt][0], atf[bt][0], racc[bt][dt], 0, 0, 0);
        racc[bt][dt] = __builtin_amdgcn_mfma_f32_16x16x32_bf16(rtf2[dt][1], atf[bt][1], racc[bt][dt], 0, 0, 0);
      }

    // 6. recv stores: (b, d = dt*16+quad*4+r) -> row b*512+nn, cols h*64+..
#pragma unroll
    for (int bt = 0; bt < 2; ++bt) {
      const int b_ = bt * 16 + la;
      unsigned short* ro = recv_out + ((size_t)(b_ * 512 + nn)) * 1024
                         + h * 64 + quad * 4;
#pragma unroll
      for (int dt = 0; dt < 4; ++dt) {
        ushort4 u;
        u.x = bf16r(racc[bt][dt][0]); u.y = bf16r(racc[bt][dt][1]);
        u.z = bf16r(racc[bt][dt][2]); u.w = bf16r(racc[bt][dt][3]);
        *(ushort4*)(ro + dt * 16) = u;
      }
    }
  }
}

// ---------------------------------------------------------------- launch
extern "C" void kernel_launch(void* const* d_in, const int* in_sizes, int n_in,
                              void* d_out, int out_size, void* d_ws, size_t ws_size,
                              hipStream_t stream) {
  const float* query  = (const float*)d_in[0];
  const float* router = (const float*)d_in[3];
  const float* Wq     = (const float*)d_in[4];
  const float* bq     = (const float*)d_in[5];
  const float* Wo     = (const float*)d_in[10];
  const float* bo     = (const float*)d_in[11];

  float* out      = (float*)d_out;                       // (B,N,D) f32
  float* attn_out = out + (size_t)Bc * Nc * Dc;          // (B,H,N,S) f32

  char* ws = (char*)d_ws;
  unsigned short* recv_b  = (unsigned short*)(ws);                 // 32 MiB
  unsigned short* query_b = (unsigned short*)(ws + 33554432u);     // 32 MiB
  unsigned short* WqTile  = (unsigned short*)(ws + 67108864u);     // 2 MiB
  unsigned short* WoTile  = (unsigned short*)(ws + 69206016u);     // 2 MiB
  unsigned short* Rg      = (unsigned short*)(ws + 71303168u);     // 4 MiB
  unsigned short* RTg     = (unsigned short*)(ws + 75497472u);     // 4 MiB

  prep      <<<10752, 256, 0, stream>>>(Wq, Wo, router, query,
                                        WqTile, WoTile, Rg, RTg, query_b);
  fused_qmid<<<512,   512, 0, stream>>>(query_b, WqTile, bq, Rg, RTg,
                                        attn_out, recv_b);
  gemm_bt   <<<(Mrows / 128) * 8, 256, 0, stream>>>(recv_b, WoTile, bo, out);
}